// Round 8
// baseline (1552.902 us; speedup 1.0000x reference)
//
#include <hip/hip_runtime.h>
#include <math.h>

// DeepArcNet fused kernel, R8: restore SROA (the R6/R7 spill root cause).
// R6/R7 post-mortem: '#pragma unroll 1' on the hh- and q2-loops made
// attn[hh*34+d] / wei[hh][s] / h[q2*34+p] runtime-indexed -> SROA failed ->
// h/attn lived in SCRATCH (VGPR_Count=120 because state wasn't in registers
// at all), wei/p promoted to LDS (+18.8KB, 295k bank conflicts), 850 MB HBM
// scratch traffic == the entire runtime.
// Fix: fully unroll hh (2 iter) and q2 (2 iter) loops -- every register-array
// index is again compile-time. The 34-iter matvec loops STAY rolled (small
// I$-resident code, results to per-lane LDS row). Weight panels staged to
// LDS (wbuf 9248 floats: Wq+Wk both heads in one stage), read as wave-
// uniform ds broadcasts. LDS 37+37=74KB -> 2 blocks/CU.

#define EMBD 68
#define NTOK 6
#define HEADD 34
#define LDSW 35                    // 34 slots + 1 pad
#define LDS_ROWS 264
#define WBUF 9248                  // two 68x68-equivalent panels

__device__ __forceinline__ float dot68l(const float (&h)[EMBD],
                                        const float* w) {   // w: LDS, 16B-aligned
    float a0 = 0.f, a1 = 0.f, a2 = 0.f, a3 = 0.f;
#pragma unroll
    for (int e = 0; e < 68; e += 4) {
        const float4 wv = *(const float4*)(w + e);
        a0 = fmaf(h[e + 0], wv.x, a0);
        a1 = fmaf(h[e + 1], wv.y, a1);
        a2 = fmaf(h[e + 2], wv.z, a2);
        a3 = fmaf(h[e + 3], wv.w, a3);
    }
    return (a0 + a1) + (a2 + a3);
}

__device__ __forceinline__ float dot34l(const float (&z)[HEADD],
                                        const float* w) {   // w: LDS, 8B-aligned
    float a0 = 0.f, a1 = 0.f;
#pragma unroll
    for (int e = 0; e < 34; e += 2) {
        const float2 wv = *(const float2*)(w + e);
        a0 = fmaf(z[e + 0], wv.x, a0);
        a1 = fmaf(z[e + 1], wv.y, a1);
    }
    return a0 + a1;
}

__device__ __forceinline__ void ln68_ip(float (&v)[EMBD],
                                        const float* __restrict__ g,
                                        const float* __restrict__ b) {
    float s1 = 0.f;
#pragma unroll
    for (int e = 0; e < EMBD; ++e) s1 += v[e];
    const float m = s1 * (1.0f / 68.0f);
    float s2 = 0.f;
#pragma unroll
    for (int e = 0; e < EMBD; ++e) { const float d = v[e] - m; s2 = fmaf(d, d, s2); }
    const float rs = rsqrtf(s2 * (1.0f / 68.0f) + 1e-5f);
#pragma unroll
    for (int e = 0; e < EMBD; ++e) v[e] = (v[e] - m) * rs * g[e] + b[e];
}

// barrier, copy N4 float4s SRC->wbuf[0..), optional second source into
// wbuf[N4..), barrier.
#define STAGE1(SRC, N4)                                                     \
    do {                                                                    \
        __syncthreads();                                                    \
        {                                                                   \
            float4* d4 = (float4*)wbuf;                                     \
            const float4* s4 = (const float4*)(SRC);                        \
            for (int i = tid; i < (N4); i += 256) d4[i] = s4[i];            \
        }                                                                   \
        __syncthreads();                                                    \
    } while (0)

#define STAGE2(SRCA, SRCB, N4)                                              \
    do {                                                                    \
        __syncthreads();                                                    \
        {                                                                   \
            float4* d4 = (float4*)wbuf;                                     \
            const float4* a4 = (const float4*)(SRCA);                       \
            const float4* b4 = (const float4*)(SRCB);                       \
            for (int i = tid; i < (N4); i += 256) d4[i] = a4[i];            \
            for (int i = tid; i < (N4); i += 256) d4[(N4) + i] = b4[i];     \
        }                                                                   \
        __syncthreads();                                                    \
    } while (0)

__global__ void __launch_bounds__(256, 1)
deeparcnet_fused(const float* __restrict__ x,        // [B,6,37,5]
                 const float* __restrict__ conv_w,   // [6,1,5,5]
                 const float* __restrict__ conv_b,   // [6]
                 const float* __restrict__ lemb_w,   // [6,4]
                 const float* __restrict__ lemb_b,   // [6,4]
                 const float* __restrict__ wq,       // [2,2,34,68]
                 const float* __restrict__ wk,
                 const float* __restrict__ wv,
                 const float* __restrict__ proj_w,   // [2,68,68]
                 const float* __restrict__ proj_b,   // [2,68]
                 const float* __restrict__ ff1_w,    // [2,34,68]
                 const float* __restrict__ ff1_b,    // [2,34]
                 const float* __restrict__ ff2_w,    // [2,68,34]
                 const float* __restrict__ ff2_b,    // [2,68]
                 const float* __restrict__ ln1_g, const float* __restrict__ ln1_b,
                 const float* __restrict__ ln2_g, const float* __restrict__ ln2_b,
                 const float* __restrict__ lnf_g, const float* __restrict__ lnf_b,
                 const float* __restrict__ fc_w,     // [6,408]
                 const float* __restrict__ fc_b,     // [6]
                 float* __restrict__ out,            // [B,6]
                 int B)
{
    __shared__ __align__(16) float rows[LDS_ROWS * LDSW];
    __shared__ __align__(16) float wbuf[WBUF];

    const int tid  = threadIdx.x;
    const int lane = tid & 63;
    const int wid  = blockIdx.x * (blockDim.x >> 6) + (tid >> 6);
    const int sub  = lane / 6;          // item slot in wave: 0..10
    const int c    = lane - sub * 6;    // token / conv channel: 0..5
    const int item = wid * 10 + sub;
    const bool active = (sub < 10) && (item < B);
    const int it = active ? item : 0;

    float* __restrict__ myrow = rows + tid * LDSW;            // lane-private
    const float* __restrict__ grow = rows + (tid - c) * LDSW; // group base

    // ---------------- conv encode + embed + pos -> h[68] -------------------
    float h[EMBD];
    {
        float xw[25];
#pragma unroll
        for (int k = 0; k < 25; ++k) xw[k] = conv_w[c * 25 + k];
        const float cb = conv_b[c];
        const float* xp = x + (size_t)(it * 6 + c) * 185;

        const float lw0 = lemb_w[c * 4 + 0], lw1 = lemb_w[c * 4 + 1];
        const float lw2 = lemb_w[c * 4 + 2], lw3 = lemb_w[c * 4 + 3];
        const float lb0 = lemb_b[c * 4 + 0], lb1 = lemb_b[c * 4 + 1];
        const float lb2 = lemb_b[c * 4 + 2], lb3 = lemb_b[c * 4 + 3];

#pragma unroll
        for (int t = 0; t < 17; ++t) {
            float a = cb;
#pragma unroll
            for (int k = 0; k < 25; ++k) a = fmaf(xp[t * 10 + k], xw[k], a);
            const float xc = fmaxf(a, 0.0f);
            const float tf = (float)t;
            h[4 * t + 0] = fmaf(xc, lw0, lb0) + __sinf(tf);
            h[4 * t + 1] = fmaf(xc, lw1, lb1) + __sinf(tf * (1.0f / 18.0f));
            h[4 * t + 2] = fmaf(xc, lw2, lb2) + __cosf(tf);
            h[4 * t + 3] = fmaf(xc, lw3, lb3) + __cosf(tf * (1.0f / 18.0f));
        }
    }

    const float qscale = 0.16903085094570331f;  // 34^-0.5

#pragma unroll 1
    for (int l = 0; l < 2; ++l) {
        const float* Wq = wq + l * (2 * HEADD * EMBD);
        const float* Wk = wk + l * (2 * HEADD * EMBD);
        const float* Wv = wv + l * (2 * HEADD * EMBD);
        const float* Pw = proj_w + l * (EMBD * EMBD);
        const float* Pb = proj_b + l * EMBD;
        const float* W1 = ff1_w + l * (HEADD * EMBD);
        const float* b1 = ff1_b + l * HEADD;
        const float* W2 = ff2_w + l * (EMBD * HEADD);
        const float* b2 = ff2_b + l * EMBD;
        const float* g1 = ln1_g + l * EMBD; const float* e1 = ln1_b + l * EMBD;
        const float* g2 = ln2_g + l * EMBD; const float* e2 = ln2_b + l * EMBD;

        // ---- scores: one stage of Wq(all)|Wk(all); hh UNROLLED ----
        STAGE2(Wq, Wk, 1156);        // wbuf[0..4624)=Wq, [4624..9248)=Wk
        float wei[2][NTOK];
#pragma unroll
        for (int hh = 0; hh < 2; ++hh) {
#pragma unroll 1
            for (int d = 0; d < HEADD; ++d)
                myrow[d] = dot68l(h, wbuf + 4624 + hh * 2312 + d * EMBD);

            float w0 = 0.f, w1 = 0.f, w2 = 0.f, w3 = 0.f, w4 = 0.f, w5 = 0.f;
#pragma unroll 1
            for (int d = 0; d < HEADD; ++d) {
                const float qd = dot68l(h, wbuf + hh * 2312 + d * EMBD);
                w0 = fmaf(qd, grow[0 * LDSW + d], w0);
                w1 = fmaf(qd, grow[1 * LDSW + d], w1);
                w2 = fmaf(qd, grow[2 * LDSW + d], w2);
                w3 = fmaf(qd, grow[3 * LDSW + d], w3);
                w4 = fmaf(qd, grow[4 * LDSW + d], w4);
                w5 = fmaf(qd, grow[5 * LDSW + d], w5);
            }
            wei[hh][0] = w0; wei[hh][1] = w1; wei[hh][2] = w2;
            wei[hh][3] = w3; wei[hh][4] = w4; wei[hh][5] = w5;
        }

        // ---- softmax (q-scale folded), hh unrolled ----
#pragma unroll
        for (int hh = 0; hh < 2; ++hh) {
            float m = wei[hh][0] * qscale;
#pragma unroll
            for (int s = 0; s < NTOK; ++s) { wei[hh][s] *= qscale; m = fmaxf(m, wei[hh][s]); }
            float sum = 0.f;
#pragma unroll
            for (int s = 0; s < NTOK; ++s) { wei[hh][s] = __expf(wei[hh][s] - m); sum += wei[hh][s]; }
            const float r = 1.0f / sum;
#pragma unroll
            for (int s = 0; s < NTOK; ++s) wei[hh][s] *= r;
        }

        // ---- attn: stage Wv (both heads); hh UNROLLED ----
        STAGE2(Wv, Wv + HEADD * EMBD, 578);
        float attn[EMBD];
#pragma unroll
        for (int hh = 0; hh < 2; ++hh) {
#pragma unroll 1
            for (int d = 0; d < HEADD; ++d)
                myrow[d] = dot68l(h, wbuf + hh * 2312 + d * EMBD);
#pragma unroll
            for (int d = 0; d < HEADD; ++d) {
                float a = wei[hh][0] * grow[0 * LDSW + d];
                a = fmaf(wei[hh][1], grow[1 * LDSW + d], a);
                a = fmaf(wei[hh][2], grow[2 * LDSW + d], a);
                a = fmaf(wei[hh][3], grow[3 * LDSW + d], a);
                a = fmaf(wei[hh][4], grow[4 * LDSW + d], a);
                a = fmaf(wei[hh][5], grow[5 * LDSW + d], a);
                attn[hh * HEADD + d] = a;
            }
        }

        // ---- proj + residual; q2 UNROLLED ----
        STAGE1(Pw, 1156);
#pragma unroll
        for (int q2 = 0; q2 < 2; ++q2) {
#pragma unroll 1
            for (int p = 0; p < HEADD; ++p)
                myrow[p] = Pb[q2 * HEADD + p] + dot68l(attn, wbuf + (q2 * HEADD + p) * EMBD);
#pragma unroll
            for (int p = 0; p < HEADD; ++p) h[q2 * HEADD + p] += myrow[p];
        }
        ln68_ip(h, g1, e1);

        // ---- ff1 + ff2 (one stage: W1 -> [0,2312), W2 -> [2312,4624)) ----
        STAGE2(W1, W2, 578);
#pragma unroll 1
        for (int f = 0; f < HEADD; ++f)
            myrow[f] = fmaxf(b1[f] + dot68l(h, wbuf + f * EMBD), 0.f);
        float z[HEADD];
#pragma unroll
        for (int f = 0; f < HEADD; ++f) z[f] = myrow[f];

#pragma unroll
        for (int q2 = 0; q2 < 2; ++q2) {
#pragma unroll 1
            for (int p = 0; p < HEADD; ++p)
                myrow[p] = b2[q2 * HEADD + p] + dot34l(z, wbuf + 2312 + (q2 * HEADD + p) * HEADD);
#pragma unroll
            for (int p = 0; p < HEADD; ++p) h[q2 * HEADD + p] += myrow[p];
        }
        ln68_ip(h, g2, e2);
    }

    // ---------------- final LN ----------------
    ln68_ip(h, lnf_g, lnf_b);

    // ---------------- fc head (stage 6x408) ----------------
    STAGE1(fc_w, 612);
    const int base_lane = sub * 6;
    float p[NTOK];
#pragma unroll
    for (int o = 0; o < NTOK; ++o)
        p[o] = dot68l(h, wbuf + o * 408 + c * EMBD);

    float tot[NTOK];
#pragma unroll
    for (int o = 0; o < NTOK; ++o) {
        float a = 0.f;
#pragma unroll
        for (int t = 0; t < NTOK; ++t) a += __shfl(p[o], base_lane + t, 64);
        tot[o] = a + fc_b[o];
    }
    float myout = tot[0];
    if (c == 1) myout = tot[1];
    if (c == 2) myout = tot[2];
    if (c == 3) myout = tot[3];
    if (c == 4) myout = tot[4];
    if (c == 5) myout = tot[5];
    if (active) out[(size_t)item * 6 + c] = fmaxf(myout, 0.f);
}

extern "C" void kernel_launch(void* const* d_in, const int* in_sizes, int n_in,
                              void* d_out, int out_size, void* d_ws, size_t ws_size,
                              hipStream_t stream) {
    const float* x      = (const float*)d_in[0];
    const float* conv_w = (const float*)d_in[1];
    const float* conv_b = (const float*)d_in[2];
    const float* lemb_w = (const float*)d_in[3];
    const float* lemb_b = (const float*)d_in[4];
    const float* wq     = (const float*)d_in[5];
    const float* wk     = (const float*)d_in[6];
    const float* wv     = (const float*)d_in[7];
    const float* proj_w = (const float*)d_in[8];
    const float* proj_b = (const float*)d_in[9];
    const float* ff1_w  = (const float*)d_in[10];
    const float* ff1_b  = (const float*)d_in[11];
    const float* ff2_w  = (const float*)d_in[12];
    const float* ff2_b  = (const float*)d_in[13];
    const float* ln1_g  = (const float*)d_in[14];
    const float* ln1_b  = (const float*)d_in[15];
    const float* ln2_g  = (const float*)d_in[16];
    const float* ln2_b  = (const float*)d_in[17];
    const float* lnf_g  = (const float*)d_in[18];
    const float* lnf_b  = (const float*)d_in[19];
    const float* fc_w   = (const float*)d_in[20];
    const float* fc_b   = (const float*)d_in[21];
    float* out = (float*)d_out;

    const int B = in_sizes[0] / (6 * 37 * 5);           // 32768
    const int waves  = (B + 9) / 10;                    // 10 items per wave
    const int blocks = (waves + 3) / 4;                 // 4 waves per block

    deeparcnet_fused<<<blocks, 256, 0, stream>>>(
        x, conv_w, conv_b, lemb_w, lemb_b, wq, wk, wv, proj_w, proj_b,
        ff1_w, ff1_b, ff2_w, ff2_b, ln1_g, ln1_b, ln2_g, ln2_b,
        lnf_g, lnf_b, fc_w, fc_b, out, B);
}